// Round 15
// baseline (127.466 us; speedup 1.0000x reference)
//
#include <hip/hip_runtime.h>
#include <hip/hip_bf16.h>
#include <stdint.h>

typedef __bf16 bf16x8 __attribute__((ext_vector_type(8)));
typedef float  f32x4  __attribute__((ext_vector_type(4)));
typedef unsigned short u16x8 __attribute__((ext_vector_type(8)));

#define NB 32
#define NC 128
#define NH 56
#define NW 56
#define NK 4
#define NCO 128
#define NCR 32
#define NHW 3136
#define TEMPER 30.0f

#define WS_ATTN   0u
#define WS_BC     4096u
#define WS_ROWSUM 65536u
#define WS_WC     1048576u
#define WS_XT     10485760u

__global__ void xt_kernel(const float* __restrict__ x, __hip_bfloat16* __restrict__ xt,
                          float* __restrict__ rowsum) {
  __shared__ float lds[58 * 133];
  int xcd = blockIdx.x & 7;
  int j   = blockIdx.x >> 3;
  int b   = xcd * 4 + j / 58;
  int hp  = j % 58;
  int blk = b * 58 + hp;
  int h = hp - 1;
  bool hin = (h >= 0) && (h < NH);
  int tid = threadIdx.x;
  if (hin) {
    const float* xrow = x + ((size_t)b * NC) * NHW + (size_t)h * NW;
    for (int i = tid; i < 128 * 14; i += 256) {
      int c = i / 14;
      int w4 = (i - c * 14) * 4;
      float4 v = *(const float4*)(xrow + (size_t)c * NHW + w4);
      int base = (w4 + 1) * 133 + c;
      lds[base]         = v.x;
      lds[base + 133]   = v.y;
      lds[base + 2*133] = v.z;
      lds[base + 3*133] = v.w;
    }
  }
  __syncthreads();
  __hip_bfloat16* orow = xt + (size_t)blk * (58 * 128);
  for (int i = tid; i < 58 * 16; i += 256) {
    int wp = i >> 4;
    int cg = (i & 15) << 3;
    u16x8 o;
    if (!hin || wp == 0 || wp == 57) {
      o = (u16x8)0;
    } else {
      const float* src = lds + wp * 133 + cg;
      #pragma unroll
      for (int jx = 0; jx < 8; ++jx) {
        union { __hip_bfloat16 b; unsigned short u; } cv;
        cv.b = __float2bfloat16(src[jx]);
        o[jx] = cv.u;
      }
    }
    *(u16x8*)(orow + wp * 128 + cg) = o;
  }
  if (hin && tid < 128) {
    float s = 0.f;
    #pragma unroll 8
    for (int wp = 1; wp <= 56; ++wp) s += lds[wp * 133 + tid];
    rowsum[(size_t)blk * 128 + tid] = s;
  }
}

__global__ void attn_kernel(const float* __restrict__ rowsum, const float* __restrict__ aw1,
                            const float* __restrict__ aw2, const float* __restrict__ bias,
                            float* __restrict__ attn, float* __restrict__ bc_out) {
  int b = blockIdx.x;
  __shared__ float sp[NC], h1[NCR], at[NK];
  int t = threadIdx.x;
  if (t < NC) {
    float s = 0.f;
    for (int hp = 1; hp <= 56; ++hp) s += rowsum[((size_t)b * 58 + hp) * 128 + t];
    sp[t] = s * (1.0f / (float)NHW);
  }
  __syncthreads();
  if (t < NCR) {
    float s = 0.f;
    for (int c = 0; c < NC; ++c) s += aw1[t*NC + c] * sp[c];
    h1[t] = s > 0.f ? s : 0.f;
  }
  __syncthreads();
  if (t == 0) {
    float lg[NK], mx = -1e30f;
    for (int k = 0; k < NK; ++k) {
      float s = 0.f;
      for (int r = 0; r < NCR; ++r) s += aw2[k*NCR + r] * h1[r];
      lg[k] = s * (1.0f/TEMPER);
      mx = fmaxf(mx, lg[k]);
    }
    float den = 0.f, e[NK];
    for (int k = 0; k < NK; ++k) { e[k] = expf(lg[k]-mx); den += e[k]; }
    float inv = 1.0f/den;
    for (int k = 0; k < NK; ++k) { at[k] = e[k]*inv; attn[b*NK+k] = at[k]; }
  }
  __syncthreads();
  if (t < NCO) {
    float s = 0.f;
    for (int k = 0; k < NK; ++k) s += at[k] * bias[k*NCO + t];
    bc_out[b*NCO + t] = s;
  }
}

__global__ void combine_kernel(const float* __restrict__ W, const float* __restrict__ attn,
                               __hip_bfloat16* __restrict__ wc) {
  int gid = blockIdx.x;
  int bg  = gid >> 6;
  int tcell = (gid & 63) * 256 + threadIdx.x;
  int co = tcell >> 7, ci = tcell & 127;
  float w[4][9];
  const float* wp = W + ((size_t)co * 128 + ci) * 9;
  #pragma unroll
  for (int k = 0; k < 4; ++k)
    #pragma unroll
    for (int j = 0; j < 9; ++j)
      w[k][j] = wp[(size_t)k * 147456 + j];
  for (int b = bg * 8; b < bg * 8 + 8; ++b) {
    float a0 = attn[b*4+0], a1 = attn[b*4+1], a2 = attn[b*4+2], a3 = attn[b*4+3];
    #pragma unroll
    for (int j = 0; j < 9; ++j) {
      float v = a0*w[0][j] + a1*w[1][j] + a2*w[2][j] + a3*w[3][j];
      wc[(((size_t)b*9 + j) * 128 + co) * 128 + ci] = __float2bfloat16(v);
    }
  }
}

// ---------------- conv: production (R13, measured 39.68us) ----------------
#define RS 2368
#define CS 40

#define GLOAD16(src, dst) \
  __builtin_amdgcn_global_load_lds( \
    (const __attribute__((address_space(1))) unsigned int*)(src), \
    (__attribute__((address_space(3))) unsigned int*)(dst), 16, 0, 0)

// Common geometry/setup shared by production + diagnostics via macro.
#define CONV_SETUP \
  const int tid  = threadIdx.x; \
  const int lane = tid & 63; \
  const int wv   = tid >> 6; \
  const int wm   = wv & 1; \
  const int wn   = wv >> 1; \
  const int bid  = blockIdx.x; \
  const int xcd  = bid & 7; \
  const int jj   = bid >> 3; \
  const int b    = xcd*4 + jj/14; \
  const int r0   = (jj % 14) * 4; \
  const int li   = lane & 15; \
  const int kg   = lane >> 4; \
  int srcB[7]; \
  _Pragma("unroll") \
  for (int i = 0; i < 7; ++i) { \
    int q = i*256 + tid; \
    int r = q / 296; \
    int sl = q - r*296; \
    int col = sl / 5; \
    int part = sl - col*5; \
    int rc = r > 5 ? 5 : r; \
    int cl = col > 57 ? 57 : col; \
    int pc = part > 3 ? 3 : part; \
    srcB[i] = ((r0 + rc)*58 + cl)*128 + pc*8; \
  } \
  int srcA[6]; \
  _Pragma("unroll") \
  for (int i = 0; i < 6; ++i) { \
    int c = i*256 + tid; \
    int kwl  = c >> 9; \
    int co   = (c & 511) >> 2; \
    int part = c & 3; \
    srcA[i] = (kwl*128 + co)*128 + part*8; \
  } \
  int xoff[7]; \
  _Pragma("unroll") \
  for (int f = 0; f < 7; ++f) { \
    int pos = wn*112 + f*16 + li; \
    int rB = pos / 56; \
    int cB = pos - rB*56; \
    xoff[f] = rB*RS + cB*CS + kg*8; \
  } \
  const int aRead = (wm*64 + li)*32 + kg*8; \
  const unsigned short* xtg = xt + (size_t)b*(58*58*128); \
  const unsigned short* wcg = wc + (size_t)b*(9*128*128);

#define LOADFRAG(AF, BF, kwl, kh) do { \
  _Pragma("unroll") \
  for (int mo = 0; mo < 4; ++mo) \
    AF[mo] = *(const bf16x8*)(lds_a + (kwl)*4096 + aRead + mo*512); \
  _Pragma("unroll") \
  for (int f = 0; f < 7; ++f) \
    BF[f] = *(const bf16x8*)(lds_b + xoff[f] + (kh)*RS + (kwl)*CS); \
} while (0)

#define PRIO_MFMA(AF, BF) do { \
  __builtin_amdgcn_s_setprio(1); \
  _Pragma("unroll") \
  for (int mo = 0; mo < 4; ++mo) \
    _Pragma("unroll") \
    for (int f = 0; f < 7; ++f) \
      acc[mo][f] = __builtin_amdgcn_mfma_f32_16x16x32_bf16(AF[mo], BF[f], acc[mo][f], 0, 0, 0); \
  __builtin_amdgcn_s_setprio(0); \
} while (0)

#define STAGE_STEP(cc, kh) do { \
  _Pragma("unroll") \
  for (int i = 0; i < 6; ++i) \
    GLOAD16(wcg + (kh)*49152 + srcA[i] + (cc)*32, lds_a + (i*256 + wv*64)*8); \
  if ((kh) == 0) { \
    _Pragma("unroll") \
    for (int i = 0; i < 7; ++i) \
      GLOAD16(xtg + srcB[i] + (cc)*32, lds_b + (i*256 + wv*64)*8); \
  } \
} while (0)

__global__ __launch_bounds__(256, 2) void conv_kernel(
    const unsigned short* __restrict__ xt,
    const unsigned short* __restrict__ wc,
    const float* __restrict__ bc,
    float* __restrict__ out) {
  __shared__ __align__(16) unsigned short lds_b[1792*8];
  __shared__ __align__(16) unsigned short lds_a[3*4096];
  CONV_SETUP
  const f32x4 vzero = {0.f, 0.f, 0.f, 0.f};
  f32x4 acc[4][7];
  #pragma unroll
  for (int mo = 0; mo < 4; ++mo)
    #pragma unroll
    for (int f = 0; f < 7; ++f) acc[mo][f] = vzero;

  for (int cc = 0; cc < 4; ++cc) {
    #pragma unroll
    for (int kh = 0; kh < 3; ++kh) {
      __syncthreads();
      STAGE_STEP(cc, kh);
      __syncthreads();
      bf16x8 afE[4], bfE[7], afO[4], bfO[7];
      LOADFRAG(afE, bfE, 0, kh);
      __builtin_amdgcn_s_barrier();
      LOADFRAG(afO, bfO, 1, kh);
      PRIO_MFMA(afE, bfE);
      __builtin_amdgcn_s_barrier();
      LOADFRAG(afE, bfE, 2, kh);
      PRIO_MFMA(afO, bfO);
      __builtin_amdgcn_s_barrier();
      PRIO_MFMA(afE, bfE);
    }
  }

  float* ob = out + (size_t)b*NCO*NHW;
  #pragma unroll
  for (int mo = 0; mo < 4; ++mo) {
    #pragma unroll
    for (int rg = 0; rg < 4; ++rg) {
      const int co = wm*64 + mo*16 + kg*4 + rg;
      const float bv = bc[b*NCO + co];
      float* orow = ob + (size_t)co*NHW;
      #pragma unroll
      for (int f = 0; f < 7; ++f) {
        int pos = wn*112 + f*16 + li;
        int rB = pos / 56;
        int cB = pos - rB*56;
        orow[(r0 + rB)*56 + cB] = acc[mo][f][rg] + bv;
      }
    }
  }
}

// ------------- diag 1: staging + barriers + ds_reads, NO MFMA -------------
__global__ __launch_bounds__(256, 2) void conv_diag_nomfma(
    const unsigned short* __restrict__ xt,
    const unsigned short* __restrict__ wc,
    const float* __restrict__ bc,
    float* __restrict__ out) {
  __shared__ __align__(16) unsigned short lds_b[1792*8];
  __shared__ __align__(16) unsigned short lds_a[3*4096];
  CONV_SETUP
  (void)bc;
  uint32_t c0 = 0, c1 = 0, c2 = 0, c3 = 0;
  #define FOLD(FR, N) do { \
    _Pragma("unroll") \
    for (int z = 0; z < (N); ++z) { \
      const uint32_t* p = (const uint32_t*)&FR[z]; \
      c0 ^= p[0]; c1 ^= p[1]; c2 ^= p[2]; c3 ^= p[3]; \
    } \
  } while (0)
  for (int cc = 0; cc < 4; ++cc) {
    #pragma unroll
    for (int kh = 0; kh < 3; ++kh) {
      __syncthreads();
      STAGE_STEP(cc, kh);
      __syncthreads();
      bf16x8 afE[4], bfE[7], afO[4], bfO[7];
      LOADFRAG(afE, bfE, 0, kh);
      __builtin_amdgcn_s_barrier();
      LOADFRAG(afO, bfO, 1, kh);
      FOLD(afE, 4); FOLD(bfE, 7);
      __builtin_amdgcn_s_barrier();
      LOADFRAG(afE, bfE, 2, kh);
      FOLD(afO, 4); FOLD(bfO, 7);
      __builtin_amdgcn_s_barrier();
      FOLD(afE, 4); FOLD(bfE, 7);
    }
  }
  union { uint32_t u; float f; } cv;
  cv.u = c0 ^ c1 ^ c2 ^ c3;
  out[bid*256 + tid] = cv.f;
}

// ---------- diag 2: staging + barriers + MFMA, ds_reads ONCE only ----------
__global__ __launch_bounds__(256, 2) void conv_diag_nodsread(
    const unsigned short* __restrict__ xt,
    const unsigned short* __restrict__ wc,
    const float* __restrict__ bc,
    float* __restrict__ out) {
  __shared__ __align__(16) unsigned short lds_b[1792*8];
  __shared__ __align__(16) unsigned short lds_a[3*4096];
  CONV_SETUP
  (void)bc;
  const f32x4 vzero = {0.f, 0.f, 0.f, 0.f};
  f32x4 acc[4][7];
  #pragma unroll
  for (int mo = 0; mo < 4; ++mo)
    #pragma unroll
    for (int f = 0; f < 7; ++f) acc[mo][f] = vzero;
  // one-time frag load after first stage
  __syncthreads();
  STAGE_STEP(0, 0);
  __syncthreads();
  bf16x8 afE[4], bfE[7];
  LOADFRAG(afE, bfE, 0, 0);
  for (int cc = 0; cc < 4; ++cc) {
    #pragma unroll
    for (int kh = 0; kh < 3; ++kh) {
      __syncthreads();
      STAGE_STEP(cc, kh);
      __syncthreads();
      __builtin_amdgcn_s_barrier();
      PRIO_MFMA(afE, bfE);
      __builtin_amdgcn_s_barrier();
      PRIO_MFMA(afE, bfE);
      __builtin_amdgcn_s_barrier();
      PRIO_MFMA(afE, bfE);
    }
  }
  float s = 0.f;
  #pragma unroll
  for (int mo = 0; mo < 4; ++mo)
    #pragma unroll
    for (int f = 0; f < 7; ++f)
      s += acc[mo][f][0] + acc[mo][f][1] + acc[mo][f][2] + acc[mo][f][3];
  out[bid*256 + tid] = s;
}

// ---------- diag 3: barriers + ds_reads + MFMA, NO global staging ----------
__global__ __launch_bounds__(256, 2) void conv_diag_nostage(
    const unsigned short* __restrict__ xt,
    const unsigned short* __restrict__ wc,
    const float* __restrict__ bc,
    float* __restrict__ out) {
  __shared__ __align__(16) unsigned short lds_b[1792*8];
  __shared__ __align__(16) unsigned short lds_a[3*4096];
  CONV_SETUP
  (void)bc; (void)xtg; (void)wcg; (void)srcA; (void)srcB;
  const f32x4 vzero = {0.f, 0.f, 0.f, 0.f};
  f32x4 acc[4][7];
  #pragma unroll
  for (int mo = 0; mo < 4; ++mo)
    #pragma unroll
    for (int f = 0; f < 7; ++f) acc[mo][f] = vzero;
  for (int cc = 0; cc < 4; ++cc) {
    #pragma unroll
    for (int kh = 0; kh < 3; ++kh) {
      __syncthreads();
      __syncthreads();
      bf16x8 afE[4], bfE[7], afO[4], bfO[7];
      LOADFRAG(afE, bfE, 0, kh);
      __builtin_amdgcn_s_barrier();
      LOADFRAG(afO, bfO, 1, kh);
      PRIO_MFMA(afE, bfE);
      __builtin_amdgcn_s_barrier();
      LOADFRAG(afE, bfE, 2, kh);
      PRIO_MFMA(afO, bfO);
      __builtin_amdgcn_s_barrier();
      PRIO_MFMA(afE, bfE);
    }
  }
  float s = 0.f;
  #pragma unroll
  for (int mo = 0; mo < 4; ++mo)
    #pragma unroll
    for (int f = 0; f < 7; ++f)
      s += acc[mo][f][0] + acc[mo][f][1] + acc[mo][f][2] + acc[mo][f][3];
  out[bid*256 + tid] = s;
}

extern "C" void kernel_launch(void* const* d_in, const int* in_sizes, int n_in,
                              void* d_out, int out_size, void* d_ws, size_t ws_size,
                              hipStream_t stream) {
  const float* x   = (const float*)d_in[0];
  const float* W   = (const float*)d_in[1];
  const float* bia = (const float*)d_in[2];
  const float* aw1 = (const float*)d_in[3];
  const float* aw2 = (const float*)d_in[4];
  float* out = (float*)d_out;
  char* ws = (char*)d_ws;
  float* attn   = (float*)(ws + WS_ATTN);
  float* bcm    = (float*)(ws + WS_BC);
  float* rowsum = (float*)(ws + WS_ROWSUM);
  __hip_bfloat16* wc = (__hip_bfloat16*)(ws + WS_WC);
  __hip_bfloat16* xt = (__hip_bfloat16*)(ws + WS_XT);
  float* sink = (float*)(ws + WS_WC);   // safe to clobber after conv_kernel

  xt_kernel<<<NB*58, 256, 0, stream>>>(x, xt, rowsum);
  attn_kernel<<<NB, 128, 0, stream>>>(rowsum, aw1, aw2, bia, attn, bcm);
  combine_kernel<<<256, 256, 0, stream>>>(W, attn, wc);
  conv_kernel<<<448, 256, 0, stream>>>((const unsigned short*)xt,
                                       (const unsigned short*)wc, bcm, out);
  // --- diagnostics (scratch sink; run after production conv) ---
  conv_diag_nomfma<<<448, 256, 0, stream>>>((const unsigned short*)xt,
                                            (const unsigned short*)wc, bcm, sink);
  conv_diag_nodsread<<<448, 256, 0, stream>>>((const unsigned short*)xt,
                                              (const unsigned short*)wc, bcm, sink);
  conv_diag_nostage<<<448, 256, 0, stream>>>((const unsigned short*)xt,
                                             (const unsigned short*)wc, bcm, sink);
}

// Round 16
// 68.309 us; speedup vs baseline: 1.8660x; 1.8660x over previous
//
#include <hip/hip_runtime.h>
#include <hip/hip_bf16.h>
#include <stdint.h>

typedef __bf16 bf16x8 __attribute__((ext_vector_type(8)));
typedef float  f32x4  __attribute__((ext_vector_type(4)));
typedef unsigned short u16x8 __attribute__((ext_vector_type(8)));

#define NB 32
#define NC 128
#define NH 56
#define NW 56
#define NK 4
#define NCO 128
#define NCR 32
#define NHW 3136
#define TEMPER 30.0f

#define WS_ATTN   0u
#define WS_BC     4096u
#define WS_ROWSUM 65536u
#define WS_WC     1048576u
#define WS_XT     10485760u

__global__ void xt_kernel(const float* __restrict__ x, __hip_bfloat16* __restrict__ xt,
                          float* __restrict__ rowsum) {
  __shared__ float lds[58 * 133];
  int xcd = blockIdx.x & 7;
  int j   = blockIdx.x >> 3;
  int b   = xcd * 4 + j / 58;
  int hp  = j % 58;
  int blk = b * 58 + hp;
  int h = hp - 1;
  bool hin = (h >= 0) && (h < NH);
  int tid = threadIdx.x;
  if (hin) {
    const float* xrow = x + ((size_t)b * NC) * NHW + (size_t)h * NW;
    for (int i = tid; i < 128 * 14; i += 256) {
      int c = i / 14;
      int w4 = (i - c * 14) * 4;
      float4 v = *(const float4*)(xrow + (size_t)c * NHW + w4);
      int base = (w4 + 1) * 133 + c;
      lds[base]         = v.x;
      lds[base + 133]   = v.y;
      lds[base + 2*133] = v.z;
      lds[base + 3*133] = v.w;
    }
  }
  __syncthreads();
  __hip_bfloat16* orow = xt + (size_t)blk * (58 * 128);
  for (int i = tid; i < 58 * 16; i += 256) {
    int wp = i >> 4;
    int cg = (i & 15) << 3;
    u16x8 o;
    if (!hin || wp == 0 || wp == 57) {
      o = (u16x8)0;
    } else {
      const float* src = lds + wp * 133 + cg;
      #pragma unroll
      for (int jx = 0; jx < 8; ++jx) {
        union { __hip_bfloat16 b; unsigned short u; } cv;
        cv.b = __float2bfloat16(src[jx]);
        o[jx] = cv.u;
      }
    }
    *(u16x8*)(orow + wp * 128 + cg) = o;
  }
  if (hin && tid < 128) {
    float s = 0.f;
    #pragma unroll 8
    for (int wp = 1; wp <= 56; ++wp) s += lds[wp * 133 + tid];
    rowsum[(size_t)blk * 128 + tid] = s;
  }
}

__global__ void attn_kernel(const float* __restrict__ rowsum, const float* __restrict__ aw1,
                            const float* __restrict__ aw2, const float* __restrict__ bias,
                            float* __restrict__ attn, float* __restrict__ bc_out) {
  int b = blockIdx.x;
  __shared__ float sp[NC], h1[NCR], at[NK];
  int t = threadIdx.x;
  if (t < NC) {
    float s = 0.f;
    for (int hp = 1; hp <= 56; ++hp) s += rowsum[((size_t)b * 58 + hp) * 128 + t];
    sp[t] = s * (1.0f / (float)NHW);
  }
  __syncthreads();
  if (t < NCR) {
    float s = 0.f;
    for (int c = 0; c < NC; ++c) s += aw1[t*NC + c] * sp[c];
    h1[t] = s > 0.f ? s : 0.f;
  }
  __syncthreads();
  if (t == 0) {
    float lg[NK], mx = -1e30f;
    for (int k = 0; k < NK; ++k) {
      float s = 0.f;
      for (int r = 0; r < NCR; ++r) s += aw2[k*NCR + r] * h1[r];
      lg[k] = s * (1.0f/TEMPER);
      mx = fmaxf(mx, lg[k]);
    }
    float den = 0.f, e[NK];
    for (int k = 0; k < NK; ++k) { e[k] = expf(lg[k]-mx); den += e[k]; }
    float inv = 1.0f/den;
    for (int k = 0; k < NK; ++k) { at[k] = e[k]*inv; attn[b*NK+k] = at[k]; }
  }
  __syncthreads();
  if (t < NCO) {
    float s = 0.f;
    for (int k = 0; k < NK; ++k) s += at[k] * bias[k*NCO + t];
    bc_out[b*NCO + t] = s;
  }
}

__global__ void combine_kernel(const float* __restrict__ W, const float* __restrict__ attn,
                               __hip_bfloat16* __restrict__ wc) {
  int gid = blockIdx.x;
  int bg  = gid >> 6;
  int tcell = (gid & 63) * 256 + threadIdx.x;
  int co = tcell >> 7, ci = tcell & 127;
  float w[4][9];
  const float* wp = W + ((size_t)co * 128 + ci) * 9;
  #pragma unroll
  for (int k = 0; k < 4; ++k)
    #pragma unroll
    for (int j = 0; j < 9; ++j)
      w[k][j] = wp[(size_t)k * 147456 + j];
  for (int b = bg * 8; b < bg * 8 + 8; ++b) {
    float a0 = attn[b*4+0], a1 = attn[b*4+1], a2 = attn[b*4+2], a3 = attn[b*4+3];
    #pragma unroll
    for (int j = 0; j < 9; ++j) {
      float v = a0*w[0][j] + a1*w[1][j] + a2*w[2][j] + a3*w[3][j];
      wc[(((size_t)b*9 + j) * 128 + co) * 128 + ci] = __float2bfloat16(v);
    }
  }
}

// ------------------------------ conv ------------------------------
// T3+T4 counted-vmcnt, FIFO-CORRECTED (the R10 bug): A staged BEFORE B at
// cc-boundaries, so every vmcnt targets a load issued >=1 full step earlier
// and the 3-step-slack B prefetch is only drained after it has landed.
// Per-thread FIFO (A=3 chunks, B=6 chunks) gives VM = 9,9,3 / 9,9,3 / 9,9,3 /
// 3,3,0 across the 12 steps (4 cc x 3 kh). Raw s_barrier pairs per step;
// never vmcnt(0) until the last step. 8 waves, wave 64co x 112pos, grid 224.
#define RS 2368            // B row stride in shorts (296 16B-slots, %8==0)
#define CS 40              // B col cell stride in shorts
#define BBUF (3072*8)      // 24,576 shorts (2960 data chunks + clamp pad)
#define ABUF (1536*8)      // 12,288 shorts ([kwl][co][32ci])

#define GLOAD16(src, dst) \
  __builtin_amdgcn_global_load_lds( \
    (const __attribute__((address_space(1))) unsigned int*)(src), \
    (__attribute__((address_space(3))) unsigned int*)(dst), 16, 0, 0)

__global__ __launch_bounds__(512, 2) void conv_kernel(
    const unsigned short* __restrict__ xt,
    const unsigned short* __restrict__ wc,
    const float* __restrict__ bc,
    float* __restrict__ out) {
  __shared__ __align__(16) unsigned short lds_a[2*ABUF];   // 49,152 B
  __shared__ __align__(16) unsigned short lds_b[2*BBUF];   // 98,304 B
  const int tid  = threadIdx.x;        // 0..511
  const int lane = tid & 63;
  const int wv   = tid >> 6;
  const int wm   = wv >> 2;            // co strip *64
  const int wn   = wv & 3;             // pos strip *112
  const int bid  = blockIdx.x;         // 224 = 8*28
  const int xcd  = bid & 7;
  const int jj   = bid >> 3;
  const int b    = xcd*4 + jj/7;
  const int r0   = (jj % 7) * 8;
  const int li   = lane & 15;
  const int kg   = lane >> 4;

  // B staging: 3072 chunks, ALL threads issue 6 (holes clamped, never read)
  int srcB[6];
  #pragma unroll
  for (int i = 0; i < 6; ++i) {
    int q = i*512 + tid;
    int r = q / 296;
    int sl = q - r*296;
    int col = sl / 5;
    int part = sl - col*5;
    int rc = r  > 9  ? 9  : r;
    int cl = col > 57 ? 57 : col;
    int pc = part > 3 ? 3 : part;
    srcB[i] = ((r0 + rc)*58 + cl)*128 + pc*8;
  }
  // A staging: 1536 chunks exact (3/thread); linear [kwl][co][32ci]
  int srcA[3];
  #pragma unroll
  for (int i = 0; i < 3; ++i) {
    int c = i*512 + tid;
    int kwl  = c >> 9;
    int co   = (c & 511) >> 2;
    int part = c & 3;
    srcA[i] = (kwl*128 + co)*128 + part*8;   // + kh*49152 + cc*32 at stage
  }

  int xoff[7];
  #pragma unroll
  for (int f = 0; f < 7; ++f) {
    int pos = wn*112 + f*16 + li;
    int rB = pos / 56;
    int cB = pos - rB*56;
    xoff[f] = rB*RS + cB*CS + kg*8;
  }
  const int aRead = (wm*64 + li)*32 + kg*8;

  const f32x4 vzero = {0.f, 0.f, 0.f, 0.f};
  f32x4 acc[4][7];
  #pragma unroll
  for (int mo = 0; mo < 4; ++mo)
    #pragma unroll
    for (int f = 0; f < 7; ++f) acc[mo][f] = vzero;

  const unsigned short* xtg = xt + (size_t)b*(58*58*128);
  const unsigned short* wcg = wc + (size_t)b*(9*128*128);

  #define STAGE_A(bufidx, ccn, khn) do { \
    unsigned short* dbase = lds_a + (bufidx)*ABUF + wv*512; \
    _Pragma("unroll") \
    for (int i = 0; i < 3; ++i) \
      GLOAD16(wcg + (khn)*49152 + srcA[i] + (ccn)*32, dbase + i*4096); \
  } while (0)

  #define STAGE_B(bufidx, ccn) do { \
    unsigned short* dbase = lds_b + (bufidx)*BBUF + wv*512; \
    _Pragma("unroll") \
    for (int i = 0; i < 6; ++i) \
      GLOAD16(xtg + srcB[i] + (ccn)*32, dbase + i*4096); \
  } while (0)

  #define LOADFRAG(AF, BF, pa, pb, kwl, kh) do { \
    _Pragma("unroll") \
    for (int mo = 0; mo < 4; ++mo) \
      AF[mo] = *(const bf16x8*)((pa) + (kwl)*4096 + aRead + mo*512); \
    _Pragma("unroll") \
    for (int f = 0; f < 7; ++f) \
      BF[f] = *(const bf16x8*)((pb) + xoff[f] + (kh)*RS + (kwl)*CS); \
  } while (0)

  #define DOMFMA(AF, BF) do { \
    __builtin_amdgcn_s_setprio(1); \
    _Pragma("unroll") \
    for (int mo = 0; mo < 4; ++mo) \
      _Pragma("unroll") \
      for (int f = 0; f < 7; ++f) \
        acc[mo][f] = __builtin_amdgcn_mfma_f32_16x16x32_bf16(AF[mo], BF[f], acc[mo][f], 0, 0, 0); \
    __builtin_amdgcn_s_setprio(0); \
  } while (0)

  // STEP s=(cc,kh): stage s+1 (A FIRST, then B at cc-starts), counted vmcnt
  // (targets loads issued a full step earlier), barrier, compute, barrier.
  #define STEP(s, cc, kh, VM) do { \
    if ((s) < 11) STAGE_A(((s)+1)&1, ((s)+1)/3, ((s)+1)%3); \
    if ((kh) == 0 && (cc) < 3) STAGE_B(((cc)+1)&1, (cc)+1); \
    asm volatile("s_waitcnt vmcnt(" #VM ")" ::: "memory"); \
    __builtin_amdgcn_s_barrier(); \
    { \
      const unsigned short* pa = lds_a + ((s)&1)*ABUF; \
      const unsigned short* pb = lds_b + ((cc)&1)*BBUF; \
      bf16x8 afE[4], bfE[7], afO[4], bfO[7]; \
      LOADFRAG(afE, bfE, pa, pb, 0, kh); \
      LOADFRAG(afO, bfO, pa, pb, 1, kh); \
      DOMFMA(afE, bfE); \
      LOADFRAG(afE, bfE, pa, pb, 2, kh); \
      DOMFMA(afO, bfO); \
      DOMFMA(afE, bfE); \
    } \
    __builtin_amdgcn_s_barrier(); \
  } while (0)

  // prologue: A0 FIRST, then B0 (FIFO order matters for the step-0 wait)
  STAGE_A(0, 0, 0);
  STAGE_B(0, 0);

  STEP(0,  0, 0, 9);
  STEP(1,  0, 1, 9);
  STEP(2,  0, 2, 3);
  STEP(3,  1, 0, 9);
  STEP(4,  1, 1, 9);
  STEP(5,  1, 2, 3);
  STEP(6,  2, 0, 9);
  STEP(7,  2, 1, 9);
  STEP(8,  2, 2, 3);
  STEP(9,  3, 0, 3);
  STEP(10, 3, 1, 3);
  STEP(11, 3, 2, 0);

  float* ob = out + (size_t)b*NCO*NHW;
  #pragma unroll
  for (int mo = 0; mo < 4; ++mo) {
    #pragma unroll
    for (int rg = 0; rg < 4; ++rg) {
      const int co = wm*64 + mo*16 + kg*4 + rg;
      const float bv = bc[b*NCO + co];
      float* orow = ob + (size_t)co*NHW;
      #pragma unroll
      for (int f = 0; f < 7; ++f) {
        int pos = wn*112 + f*16 + li;
        int rB = pos / 56;
        int cB = pos - rB*56;
        orow[(r0 + rB)*56 + cB] = acc[mo][f][rg] + bv;
      }
    }
  }
}

extern "C" void kernel_launch(void* const* d_in, const int* in_sizes, int n_in,
                              void* d_out, int out_size, void* d_ws, size_t ws_size,
                              hipStream_t stream) {
  const float* x   = (const float*)d_in[0];
  const float* W   = (const float*)d_in[1];
  const float* bia = (const float*)d_in[2];
  const float* aw1 = (const float*)d_in[3];
  const float* aw2 = (const float*)d_in[4];
  float* out = (float*)d_out;
  char* ws = (char*)d_ws;
  float* attn   = (float*)(ws + WS_ATTN);
  float* bcm    = (float*)(ws + WS_BC);
  float* rowsum = (float*)(ws + WS_ROWSUM);
  __hip_bfloat16* wc = (__hip_bfloat16*)(ws + WS_WC);
  __hip_bfloat16* xt = (__hip_bfloat16*)(ws + WS_XT);

  xt_kernel<<<NB*58, 256, 0, stream>>>(x, xt, rowsum);
  attn_kernel<<<NB, 128, 0, stream>>>(rowsum, aw1, aw2, bia, attn, bcm);
  combine_kernel<<<256, 256, 0, stream>>>(W, attn, wc);
  conv_kernel<<<224, 512, 0, stream>>>((const unsigned short*)xt,
                                       (const unsigned short*)wc, bcm, out);
}

// Round 17
// 67.411 us; speedup vs baseline: 1.8909x; 1.0133x over previous
//
#include <hip/hip_runtime.h>
#include <hip/hip_bf16.h>
#include <stdint.h>

typedef __bf16 bf16x8 __attribute__((ext_vector_type(8)));
typedef float  f32x4  __attribute__((ext_vector_type(4)));
typedef unsigned short u16x8 __attribute__((ext_vector_type(8)));
typedef unsigned int   u32x4 __attribute__((ext_vector_type(4)));

#define NB 32
#define NC 128
#define NH 56
#define NW 56
#define NK 4
#define NCO 128
#define NCR 32
#define NHW 3136
#define TEMPER 30.0f

#define WS_ATTN   0u
#define WS_BC     4096u
#define WS_ROWSUM 65536u
#define WS_WC     1048576u
#define WS_XT     10485760u

__global__ void xt_kernel(const float* __restrict__ x, __hip_bfloat16* __restrict__ xt,
                          float* __restrict__ rowsum) {
  __shared__ float lds[58 * 133];
  int xcd = blockIdx.x & 7;
  int j   = blockIdx.x >> 3;
  int b   = xcd * 4 + j / 58;
  int hp  = j % 58;
  int blk = b * 58 + hp;
  int h = hp - 1;
  bool hin = (h >= 0) && (h < NH);
  int tid = threadIdx.x;
  if (hin) {
    const float* xrow = x + ((size_t)b * NC) * NHW + (size_t)h * NW;
    for (int i = tid; i < 128 * 14; i += 256) {
      int c = i / 14;
      int w4 = (i - c * 14) * 4;
      float4 v = *(const float4*)(xrow + (size_t)c * NHW + w4);
      int base = (w4 + 1) * 133 + c;
      lds[base]         = v.x;
      lds[base + 133]   = v.y;
      lds[base + 2*133] = v.z;
      lds[base + 3*133] = v.w;
    }
  }
  __syncthreads();
  __hip_bfloat16* orow = xt + (size_t)blk * (58 * 128);
  for (int i = tid; i < 58 * 16; i += 256) {
    int wp = i >> 4;
    int cg = (i & 15) << 3;
    u16x8 o;
    if (!hin || wp == 0 || wp == 57) {
      o = (u16x8)0;
    } else {
      const float* src = lds + wp * 133 + cg;
      #pragma unroll
      for (int jx = 0; jx < 8; ++jx) {
        union { __hip_bfloat16 b; unsigned short u; } cv;
        cv.b = __float2bfloat16(src[jx]);
        o[jx] = cv.u;
      }
    }
    *(u16x8*)(orow + wp * 128 + cg) = o;
  }
  if (hin && tid < 128) {
    float s = 0.f;
    #pragma unroll 8
    for (int wp = 1; wp <= 56; ++wp) s += lds[wp * 133 + tid];
    rowsum[(size_t)blk * 128 + tid] = s;
  }
}

__global__ void attn_kernel(const float* __restrict__ rowsum, const float* __restrict__ aw1,
                            const float* __restrict__ aw2, const float* __restrict__ bias,
                            float* __restrict__ attn, float* __restrict__ bc_out) {
  int b = blockIdx.x;
  __shared__ float sp[NC], h1[NCR], at[NK];
  int t = threadIdx.x;
  if (t < NC) {
    float s = 0.f;
    for (int hp = 1; hp <= 56; ++hp) s += rowsum[((size_t)b * 58 + hp) * 128 + t];
    sp[t] = s * (1.0f / (float)NHW);
  }
  __syncthreads();
  if (t < NCR) {
    float s = 0.f;
    for (int c = 0; c < NC; ++c) s += aw1[t*NC + c] * sp[c];
    h1[t] = s > 0.f ? s : 0.f;
  }
  __syncthreads();
  if (t == 0) {
    float lg[NK], mx = -1e30f;
    for (int k = 0; k < NK; ++k) {
      float s = 0.f;
      for (int r = 0; r < NCR; ++r) s += aw2[k*NCR + r] * h1[r];
      lg[k] = s * (1.0f/TEMPER);
      mx = fmaxf(mx, lg[k]);
    }
    float den = 0.f, e[NK];
    for (int k = 0; k < NK; ++k) { e[k] = expf(lg[k]-mx); den += e[k]; }
    float inv = 1.0f/den;
    for (int k = 0; k < NK; ++k) { at[k] = e[k]*inv; attn[b*NK+k] = at[k]; }
  }
  __syncthreads();
  if (t < NCO) {
    float s = 0.f;
    for (int k = 0; k < NK; ++k) s += at[k] * bias[k*NCO + t];
    bc_out[b*NCO + t] = s;
  }
}

__global__ void combine_kernel(const float* __restrict__ W, const float* __restrict__ attn,
                               __hip_bfloat16* __restrict__ wc) {
  int gid = blockIdx.x;
  int bg  = gid >> 6;
  int tcell = (gid & 63) * 256 + threadIdx.x;
  int co = tcell >> 7, ci = tcell & 127;
  float w[4][9];
  const float* wp = W + ((size_t)co * 128 + ci) * 9;
  #pragma unroll
  for (int k = 0; k < 4; ++k)
    #pragma unroll
    for (int j = 0; j < 9; ++j)
      w[k][j] = wp[(size_t)k * 147456 + j];
  for (int b = bg * 8; b < bg * 8 + 8; ++b) {
    float a0 = attn[b*4+0], a1 = attn[b*4+1], a2 = attn[b*4+2], a3 = attn[b*4+3];
    #pragma unroll
    for (int j = 0; j < 9; ++j) {
      float v = a0*w[0][j] + a1*w[1][j] + a2*w[2][j] + a3*w[3][j];
      wc[(((size_t)b*9 + j) * 128 + co) * 128 + ci] = __float2bfloat16(v);
    }
  }
}

// ------------------------------ conv ------------------------------
// REG-STAGED double-buffered pipeline (T14 issue-early/write-late).
// Mechanism fix for the 40us invariant: with global_load_lds prefetch, the
// compiler cannot prove the in-flight LDS writes don't alias the current
// buffer's ds_reads, so it inserts its own vmcnt(0) before the MFMAs --
// draining every prefetch (this defeated R8/R10/R15). With global->VGPR
// loads, the vmcnt dependency attaches ONLY to the ds_write that consumes
// the register, after compute. Staging now truly overlaps compute.
// Per step: issue s+1 loads -> compute (pure ds_read+MFMA) -> barrier ->
// ds_write regs into buf[s+1] -> barrier. 12 steps (4cc x 3kh).
// 8 waves, wave 64co x 112pos, grid 224 (8 XCD x 28), LDS 147KB dbuf.
#define RS 2368            // B row stride in shorts (296 16B-slots, %8==0)
#define CS 40              // B col cell stride in shorts
#define BBUF (3072*8)      // 24,576 shorts (2960 data chunks + clamp pad)
#define ABUF (1536*8)      // 12,288 shorts ([kwl][co][32ci])

__global__ __launch_bounds__(512, 2) void conv_kernel(
    const unsigned short* __restrict__ xt,
    const unsigned short* __restrict__ wc,
    const float* __restrict__ bc,
    float* __restrict__ out) {
  __shared__ __align__(16) unsigned short lds_a[2*ABUF];   // 49,152 B
  __shared__ __align__(16) unsigned short lds_b[2*BBUF];   // 98,304 B
  const int tid  = threadIdx.x;        // 0..511
  const int lane = tid & 63;
  const int wv   = tid >> 6;
  const int wm   = wv >> 2;            // co strip *64
  const int wn   = wv & 3;             // pos strip *112
  const int bid  = blockIdx.x;         // 224 = 8*28
  const int xcd  = bid & 7;
  const int jj   = bid >> 3;
  const int b    = xcd*4 + jj/7;
  const int r0   = (jj % 7) * 8;
  const int li   = lane & 15;
  const int kg   = lane >> 4;

  // B staging: 3072 chunks (6/thread; holes clamped in-bounds, never read)
  int srcB[6];
  #pragma unroll
  for (int i = 0; i < 6; ++i) {
    int q = i*512 + tid;
    int r = q / 296;
    int sl = q - r*296;
    int col = sl / 5;
    int part = sl - col*5;
    int rc = r  > 9  ? 9  : r;
    int cl = col > 57 ? 57 : col;
    int pc = part > 3 ? 3 : part;
    srcB[i] = ((r0 + rc)*58 + cl)*128 + pc*8;
  }
  // A staging: 1536 chunks exact (3/thread); linear [kwl][co][32ci]
  int srcA[3];
  #pragma unroll
  for (int i = 0; i < 3; ++i) {
    int c = i*512 + tid;
    int kwl  = c >> 9;
    int co   = (c & 511) >> 2;
    int part = c & 3;
    srcA[i] = (kwl*128 + co)*128 + part*8;   // + kh*49152 + cc*32 at stage
  }

  int xoff[7];
  #pragma unroll
  for (int f = 0; f < 7; ++f) {
    int pos = wn*112 + f*16 + li;
    int rB = pos / 56;
    int cB = pos - rB*56;
    xoff[f] = rB*RS + cB*CS + kg*8;
  }
  const int aRead = (wm*64 + li)*32 + kg*8;

  const f32x4 vzero = {0.f, 0.f, 0.f, 0.f};
  f32x4 acc[4][7];
  #pragma unroll
  for (int mo = 0; mo < 4; ++mo)
    #pragma unroll
    for (int f = 0; f < 7; ++f) acc[mo][f] = vzero;

  const unsigned short* xtg = xt + (size_t)b*(58*58*128);
  const unsigned short* wcg = wc + (size_t)b*(9*128*128);

  u32x4 aST[3], bST[6];

  #define LOAD_A(ccn, khn) do { \
    _Pragma("unroll") \
    for (int i = 0; i < 3; ++i) \
      aST[i] = *(const u32x4*)(wcg + (khn)*49152 + srcA[i] + (ccn)*32); \
  } while (0)

  #define LOAD_B(ccn) do { \
    _Pragma("unroll") \
    for (int i = 0; i < 6; ++i) \
      bST[i] = *(const u32x4*)(xtg + srcB[i] + (ccn)*32); \
  } while (0)

  #define WRITE_A(bufidx) do { \
    _Pragma("unroll") \
    for (int i = 0; i < 3; ++i) \
      *(u32x4*)(lds_a + (bufidx)*ABUF + (i*512 + tid)*8) = aST[i]; \
  } while (0)

  #define WRITE_B(bufidx) do { \
    _Pragma("unroll") \
    for (int i = 0; i < 6; ++i) \
      *(u32x4*)(lds_b + (bufidx)*BBUF + (i*512 + tid)*8) = bST[i]; \
  } while (0)

  #define COMPUTE(s, cc, kh) do { \
    const unsigned short* pa = lds_a + ((s)&1)*ABUF; \
    const unsigned short* pb = lds_b + ((cc)&1)*BBUF; \
    _Pragma("unroll") \
    for (int kwl = 0; kwl < 3; ++kwl) { \
      bf16x8 af[4], bf[7]; \
      _Pragma("unroll") \
      for (int mo = 0; mo < 4; ++mo) \
        af[mo] = *(const bf16x8*)(pa + kwl*4096 + aRead + mo*512); \
      _Pragma("unroll") \
      for (int f = 0; f < 7; ++f) \
        bf[f] = *(const bf16x8*)(pb + xoff[f] + (kh)*RS + kwl*CS); \
      __builtin_amdgcn_s_setprio(1); \
      _Pragma("unroll") \
      for (int mo = 0; mo < 4; ++mo) \
        _Pragma("unroll") \
        for (int f = 0; f < 7; ++f) \
          acc[mo][f] = __builtin_amdgcn_mfma_f32_16x16x32_bf16(af[mo], bf[f], acc[mo][f], 0, 0, 0); \
      __builtin_amdgcn_s_setprio(0); \
    } \
  } while (0)

  // STEP s: issue s+1 loads -> compute s -> barrier -> ds_write bufs -> barrier
  #define STEP(s, cc, kh) do { \
    if ((s) < 11) LOAD_A(((s)+1)/3, ((s)+1)%3); \
    if ((kh) == 0 && (cc) < 3) LOAD_B((cc)+1); \
    COMPUTE(s, cc, kh); \
    __syncthreads(); \
    if ((s) < 11) WRITE_A(((s)+1)&1); \
    if ((kh) == 0 && (cc) < 3) WRITE_B(((cc)+1)&1); \
    __syncthreads(); \
  } while (0)

  // prologue: stage step-0 buffers via regs
  LOAD_A(0, 0);
  LOAD_B(0);
  WRITE_A(0);
  WRITE_B(0);
  __syncthreads();

  STEP(0,  0, 0);
  STEP(1,  0, 1);
  STEP(2,  0, 2);
  STEP(3,  1, 0);
  STEP(4,  1, 1);
  STEP(5,  1, 2);
  STEP(6,  2, 0);
  STEP(7,  2, 1);
  STEP(8,  2, 2);
  STEP(9,  3, 0);
  STEP(10, 3, 1);
  STEP(11, 3, 2);

  float* ob = out + (size_t)b*NCO*NHW;
  #pragma unroll
  for (int mo = 0; mo < 4; ++mo) {
    #pragma unroll
    for (int rg = 0; rg < 4; ++rg) {
      const int co = wm*64 + mo*16 + kg*4 + rg;
      const float bv = bc[b*NCO + co];
      float* orow = ob + (size_t)co*NHW;
      #pragma unroll
      for (int f = 0; f < 7; ++f) {
        int pos = wn*112 + f*16 + li;
        int rB = pos / 56;
        int cB = pos - rB*56;
        orow[(r0 + rB)*56 + cB] = acc[mo][f][rg] + bv;
      }
    }
  }
}

extern "C" void kernel_launch(void* const* d_in, const int* in_sizes, int n_in,
                              void* d_out, int out_size, void* d_ws, size_t ws_size,
                              hipStream_t stream) {
  const float* x   = (const float*)d_in[0];
  const float* W   = (const float*)d_in[1];
  const float* bia = (const float*)d_in[2];
  const float* aw1 = (const float*)d_in[3];
  const float* aw2 = (const float*)d_in[4];
  float* out = (float*)d_out;
  char* ws = (char*)d_ws;
  float* attn   = (float*)(ws + WS_ATTN);
  float* bcm    = (float*)(ws + WS_BC);
  float* rowsum = (float*)(ws + WS_ROWSUM);
  __hip_bfloat16* wc = (__hip_bfloat16*)(ws + WS_WC);
  __hip_bfloat16* xt = (__hip_bfloat16*)(ws + WS_XT);

  xt_kernel<<<NB*58, 256, 0, stream>>>(x, xt, rowsum);
  attn_kernel<<<NB, 128, 0, stream>>>(rowsum, aw1, aw2, bia, attn, bcm);
  combine_kernel<<<256, 256, 0, stream>>>(W, attn, wc);
  conv_kernel<<<224, 512, 0, stream>>>((const unsigned short*)xt,
                                       (const unsigned short*)wc, bcm, out);
}

// Round 18
// 66.355 us; speedup vs baseline: 1.9210x; 1.0159x over previous
//
#include <hip/hip_runtime.h>
#include <hip/hip_bf16.h>
#include <stdint.h>

typedef __bf16 bf16x8 __attribute__((ext_vector_type(8)));
typedef float  f32x4  __attribute__((ext_vector_type(4)));
typedef unsigned short u16x8 __attribute__((ext_vector_type(8)));

#define NB 32
#define NC 128
#define NH 56
#define NW 56
#define NK 4
#define NCO 128
#define NCR 32
#define NHW 3136
#define TEMPER 30.0f

#define WS_ATTN   0u
#define WS_BC     4096u
#define WS_ROWSUM 65536u
#define WS_WC     1048576u
#define WS_XT     10485760u

__global__ void xt_kernel(const float* __restrict__ x, __hip_bfloat16* __restrict__ xt,
                          float* __restrict__ rowsum) {
  __shared__ float lds[58 * 133];
  int xcd = blockIdx.x & 7;
  int j   = blockIdx.x >> 3;
  int b   = xcd * 4 + j / 58;
  int hp  = j % 58;
  int blk = b * 58 + hp;
  int h = hp - 1;
  bool hin = (h >= 0) && (h < NH);
  int tid = threadIdx.x;
  if (hin) {
    const float* xrow = x + ((size_t)b * NC) * NHW + (size_t)h * NW;
    for (int i = tid; i < 128 * 14; i += 256) {
      int c = i / 14;
      int w4 = (i - c * 14) * 4;
      float4 v = *(const float4*)(xrow + (size_t)c * NHW + w4);
      int base = (w4 + 1) * 133 + c;
      lds[base]         = v.x;
      lds[base + 133]   = v.y;
      lds[base + 2*133] = v.z;
      lds[base + 3*133] = v.w;
    }
  }
  __syncthreads();
  __hip_bfloat16* orow = xt + (size_t)blk * (58 * 128);
  for (int i = tid; i < 58 * 16; i += 256) {
    int wp = i >> 4;
    int cg = (i & 15) << 3;
    u16x8 o;
    if (!hin || wp == 0 || wp == 57) {
      o = (u16x8)0;
    } else {
      const float* src = lds + wp * 133 + cg;
      #pragma unroll
      for (int jx = 0; jx < 8; ++jx) {
        union { __hip_bfloat16 b; unsigned short u; } cv;
        cv.b = __float2bfloat16(src[jx]);
        o[jx] = cv.u;
      }
    }
    *(u16x8*)(orow + wp * 128 + cg) = o;
  }
  if (hin && tid < 128) {
    float s = 0.f;
    #pragma unroll 8
    for (int wp = 1; wp <= 56; ++wp) s += lds[wp * 133 + tid];
    rowsum[(size_t)blk * 128 + tid] = s;
  }
}

__global__ void attn_kernel(const float* __restrict__ rowsum, const float* __restrict__ aw1,
                            const float* __restrict__ aw2, const float* __restrict__ bias,
                            float* __restrict__ attn, float* __restrict__ bc_out) {
  int b = blockIdx.x;
  __shared__ float sp[NC], h1[NCR], at[NK];
  int t = threadIdx.x;
  if (t < NC) {
    float s = 0.f;
    for (int hp = 1; hp <= 56; ++hp) s += rowsum[((size_t)b * 58 + hp) * 128 + t];
    sp[t] = s * (1.0f / (float)NHW);
  }
  __syncthreads();
  if (t < NCR) {
    float s = 0.f;
    for (int c = 0; c < NC; ++c) s += aw1[t*NC + c] * sp[c];
    h1[t] = s > 0.f ? s : 0.f;
  }
  __syncthreads();
  if (t == 0) {
    float lg[NK], mx = -1e30f;
    for (int k = 0; k < NK; ++k) {
      float s = 0.f;
      for (int r = 0; r < NCR; ++r) s += aw2[k*NCR + r] * h1[r];
      lg[k] = s * (1.0f/TEMPER);
      mx = fmaxf(mx, lg[k]);
    }
    float den = 0.f, e[NK];
    for (int k = 0; k < NK; ++k) { e[k] = expf(lg[k]-mx); den += e[k]; }
    float inv = 1.0f/den;
    for (int k = 0; k < NK; ++k) { at[k] = e[k]*inv; attn[b*NK+k] = at[k]; }
  }
  __syncthreads();
  if (t < NCO) {
    float s = 0.f;
    for (int k = 0; k < NK; ++k) s += at[k] * bias[k*NCO + t];
    bc_out[b*NCO + t] = s;
  }
}

__global__ void combine_kernel(const float* __restrict__ W, const float* __restrict__ attn,
                               __hip_bfloat16* __restrict__ wc) {
  int gid = blockIdx.x;
  int bg  = gid >> 6;
  int tcell = (gid & 63) * 256 + threadIdx.x;
  int co = tcell >> 7, ci = tcell & 127;
  float w[4][9];
  const float* wp = W + ((size_t)co * 128 + ci) * 9;
  #pragma unroll
  for (int k = 0; k < 4; ++k)
    #pragma unroll
    for (int j = 0; j < 9; ++j)
      w[k][j] = wp[(size_t)k * 147456 + j];
  for (int b = bg * 8; b < bg * 8 + 8; ++b) {
    float a0 = attn[b*4+0], a1 = attn[b*4+1], a2 = attn[b*4+2], a3 = attn[b*4+3];
    #pragma unroll
    for (int j = 0; j < 9; ++j) {
      float v = a0*w[0][j] + a1*w[1][j] + a2*w[2][j] + a3*w[3][j];
      wc[(((size_t)b*9 + j) * 128 + co) * 128 + ci] = __float2bfloat16(v);
    }
  }
}

// ------------------------------ conv ------------------------------
// R13 serial-staged structure + SCHED_BARRIER-FENCED compute pipeline.
// Diagnosis (R16/R17 VGPR evidence): compiler was sinking all "pipelined"
// fragment loads back to just-before-use (VGPR 128 << live set 220), so
// every wave ran [11 ds_read -> wait -> 28 MFMA] in convoy and the LDS and
// matrix pipes alternated. sched_barrier(0) makes the sink illegal: reads
// for group g+1 are ISSUED before group g's MFMAs, so they are serviced
// concurrently (compiler still inserts counted lgkmcnt). VGPR must rise to
// ~210-230 (observable check), still under the 256 cap at 2 waves/SIMD.
// Block = 128co x 224pos (4 out rows), 4 waves, grid 448, 2 blocks/CU.
#define RS 2368            // B row stride in shorts (296 16B-slots, %8==0)
#define CS 40              // B col cell stride in shorts

#define GLOAD16(src, dst) \
  __builtin_amdgcn_global_load_lds( \
    (const __attribute__((address_space(1))) unsigned int*)(src), \
    (__attribute__((address_space(3))) unsigned int*)(dst), 16, 0, 0)

#define SB() __builtin_amdgcn_sched_barrier(0)

__global__ __launch_bounds__(256, 2) void conv_kernel(
    const unsigned short* __restrict__ xt,
    const unsigned short* __restrict__ wc,
    const float* __restrict__ bc,
    float* __restrict__ out) {
  __shared__ __align__(16) unsigned short lds_b[1792*8];   // 28,672 B
  __shared__ __align__(16) unsigned short lds_a[3*4096];   // 24,576 B [kwl][co][32ci]
  const int tid  = threadIdx.x;
  const int lane = tid & 63;
  const int wv   = tid >> 6;
  const int wm   = wv & 1;
  const int wn   = wv >> 1;
  const int bid  = blockIdx.x;         // 448 = 8 xcd * 56
  const int xcd  = bid & 7;
  const int jj   = bid >> 3;
  const int b    = xcd*4 + jj/14;
  const int r0   = (jj % 14) * 4;
  const int li   = lane & 15;
  const int kg   = lane >> 4;

  int srcB[7];
  #pragma unroll
  for (int i = 0; i < 7; ++i) {
    int q = i*256 + tid;
    int r = q / 296;
    int sl = q - r*296;
    int col = sl / 5;
    int part = sl - col*5;
    int rc = r > 5 ? 5 : r;
    int cl = col > 57 ? 57 : col;
    int pc = part > 3 ? 3 : part;
    srcB[i] = ((r0 + rc)*58 + cl)*128 + pc*8;
  }
  int srcA[6];
  #pragma unroll
  for (int i = 0; i < 6; ++i) {
    int c = i*256 + tid;
    int kwl  = c >> 9;
    int co   = (c & 511) >> 2;
    int part = c & 3;
    srcA[i] = (kwl*128 + co)*128 + part*8;   // + kh*49152 + cc*32 at stage
  }

  int xoff[7];
  #pragma unroll
  for (int f = 0; f < 7; ++f) {
    int pos = wn*112 + f*16 + li;
    int rB = pos / 56;
    int cB = pos - rB*56;
    xoff[f] = rB*RS + cB*CS + kg*8;
  }
  const int aRead = (wm*64 + li)*32 + kg*8;

  const f32x4 vzero = {0.f, 0.f, 0.f, 0.f};
  f32x4 acc[4][7];
  #pragma unroll
  for (int mo = 0; mo < 4; ++mo)
    #pragma unroll
    for (int f = 0; f < 7; ++f) acc[mo][f] = vzero;

  const unsigned short* xtg = xt + (size_t)b*(58*58*128);
  const unsigned short* wcg = wc + (size_t)b*(9*128*128);

  #define LOADFRAG(AF, BF, kwl, kh) do { \
    _Pragma("unroll") \
    for (int mo = 0; mo < 4; ++mo) \
      AF[mo] = *(const bf16x8*)(lds_a + (kwl)*4096 + aRead + mo*512); \
    _Pragma("unroll") \
    for (int f = 0; f < 7; ++f) \
      BF[f] = *(const bf16x8*)(lds_b + xoff[f] + (kh)*RS + (kwl)*CS); \
  } while (0)

  #define DOMFMA(AF, BF) do { \
    __builtin_amdgcn_s_setprio(1); \
    _Pragma("unroll") \
    for (int mo = 0; mo < 4; ++mo) \
      _Pragma("unroll") \
      for (int f = 0; f < 7; ++f) \
        acc[mo][f] = __builtin_amdgcn_mfma_f32_16x16x32_bf16(AF[mo], BF[f], acc[mo][f], 0, 0, 0); \
    __builtin_amdgcn_s_setprio(0); \
  } while (0)

  for (int cc = 0; cc < 4; ++cc) {
    #pragma unroll
    for (int kh = 0; kh < 3; ++kh) {
      __syncthreads();                 // readers of lds_a/lds_b done
      #pragma unroll
      for (int i = 0; i < 6; ++i)
        GLOAD16(wcg + kh*49152 + srcA[i] + cc*32, lds_a + (i*256 + wv*64)*8);
      if (kh == 0) {
        #pragma unroll
        for (int i = 0; i < 7; ++i)
          GLOAD16(xtg + srcB[i] + cc*32, lds_b + (i*256 + wv*64)*8);
      }
      __syncthreads();                 // staged data ready

      // Fenced software pipeline: reads of group g+1 ISSUE before MFMAs of
      // group g; sched_barrier(0) makes compiler sinking illegal.
      bf16x8 afE[4], bfE[7], afO[4], bfO[7];
      LOADFRAG(afE, bfE, 0, kh);
      SB();
      LOADFRAG(afO, bfO, 1, kh);
      SB();
      DOMFMA(afE, bfE);                // overlaps kwl=1 reads in flight
      SB();
      LOADFRAG(afE, bfE, 2, kh);
      SB();
      DOMFMA(afO, bfO);                // overlaps kwl=2 reads in flight
      SB();
      DOMFMA(afE, bfE);
    }
  }

  float* ob = out + (size_t)b*NCO*NHW;
  #pragma unroll
  for (int mo = 0; mo < 4; ++mo) {
    #pragma unroll
    for (int rg = 0; rg < 4; ++rg) {
      const int co = wm*64 + mo*16 + kg*4 + rg;
      const float bv = bc[b*NCO + co];
      float* orow = ob + (size_t)co*NHW;
      #pragma unroll
      for (int f = 0; f < 7; ++f) {
        int pos = wn*112 + f*16 + li;
        int rB = pos / 56;
        int cB = pos - rB*56;
        orow[(r0 + rB)*56 + cB] = acc[mo][f][rg] + bv;
      }
    }
  }
}

extern "C" void kernel_launch(void* const* d_in, const int* in_sizes, int n_in,
                              void* d_out, int out_size, void* d_ws, size_t ws_size,
                              hipStream_t stream) {
  const float* x   = (const float*)d_in[0];
  const float* W   = (const float*)d_in[1];
  const float* bia = (const float*)d_in[2];
  const float* aw1 = (const float*)d_in[3];
  const float* aw2 = (const float*)d_in[4];
  float* out = (float*)d_out;
  char* ws = (char*)d_ws;
  float* attn   = (float*)(ws + WS_ATTN);
  float* bcm    = (float*)(ws + WS_BC);
  float* rowsum = (float*)(ws + WS_ROWSUM);
  __hip_bfloat16* wc = (__hip_bfloat16*)(ws + WS_WC);
  __hip_bfloat16* xt = (__hip_bfloat16*)(ws + WS_XT);

  xt_kernel<<<NB*58, 256, 0, stream>>>(x, xt, rowsum);
  attn_kernel<<<NB, 128, 0, stream>>>(rowsum, aw1, aw2, bia, attn, bcm);
  combine_kernel<<<256, 256, 0, stream>>>(W, attn, wc);
  conv_kernel<<<448, 256, 0, stream>>>((const unsigned short*)xt,
                                       (const unsigned short*)wc, bcm, out);
}